// Round 2
// baseline (7402.483 us; speedup 1.0000x reference)
//
#include <hip/hip_runtime.h>
#include <math.h>

#define Bn 64
#define Tn 512
#define Dn 256
#define Hn 256
#define Gn 1024   // 4*H

typedef _Float16 f16x2 __attribute__((ext_vector_type(2)));
typedef short bf16x8 __attribute__((ext_vector_type(8)));
typedef float f32x4 __attribute__((ext_vector_type(4)));

union U32H2 { unsigned int u; f16x2 h; };

__device__ __forceinline__ f16x2 u2h(unsigned int u) { U32H2 v; v.u = u; return v.h; }
__device__ __forceinline__ unsigned int packh2(float x, float y) {
    U32H2 v; v.h = (f16x2){(_Float16)x, (_Float16)y}; return v.u;
}

// fp32 -> bf16 round-to-nearest-even
__device__ __forceinline__ unsigned short f2bf(float x) {
    unsigned int u = __float_as_uint(x);
    u = u + 0x7FFFu + ((u >> 16) & 1u);
    return (unsigned short)(u >> 16);
}

#if __has_builtin(__builtin_amdgcn_fdot2)
__device__ __forceinline__ float fdot2f(f16x2 a, f16x2 b, float c) {
    return __builtin_amdgcn_fdot2(a, b, c, false);
}
#else
__device__ __forceinline__ float fdot2f(f16x2 a, f16x2 b, float c) {
    return fmaf((float)a[1], (float)b[1], fmaf((float)a[0], (float)b[0], c));
}
#endif

__device__ __forceinline__ float sigm(float x) { return 1.0f / (1.0f + __expf(-x)); }

// ---------------------------------------------------------------------------
// W_c[g][k] (bf16) = sum_d W_ih[g][d]*W_att[d][k];  bias_c[g] = W_ih[g]·b_att + b_ih[g] + b_hh[g]
// ---------------------------------------------------------------------------
__global__ void k_wc(const float* __restrict__ W_ih, const float* __restrict__ W_att,
                     const float* __restrict__ b_att, const float* __restrict__ b_ih,
                     const float* __restrict__ b_hh,
                     unsigned short* __restrict__ W_cb, float* __restrict__ bias_c) {
    int g = blockIdx.x;
    int k = threadIdx.x;
    __shared__ float wih_s[Dn];
    __shared__ float red[256];
    wih_s[k] = W_ih[g * Dn + k];
    __syncthreads();
    float acc = 0.0f;
    for (int d = 0; d < Dn; ++d)
        acc = fmaf(wih_s[d], W_att[d * Dn + k], acc);
    W_cb[g * Dn + k] = f2bf(acc);
    red[k] = wih_s[k] * b_att[k];
    __syncthreads();
    for (int s = 128; s > 0; s >>= 1) {
        if (k < s) red[k] += red[k + s];
        __syncthreads();
    }
    if (k == 0) bias_c[g] = red[0] + b_ih[g] + b_hh[g];
}

// ---------------------------------------------------------------------------
// vlin0[b][d] = values[b,0,:]·W_att[d,:] + b_att[d]
// ---------------------------------------------------------------------------
__global__ void k_vlin0(const float* __restrict__ values, const float* __restrict__ W_att,
                        const float* __restrict__ b_att, float* __restrict__ vlin0) {
    int b = blockIdx.x, d = threadIdx.x;
    __shared__ float v_s[Dn];
    v_s[d] = values[(size_t)b * Tn * Dn + d];
    __syncthreads();
    float acc = b_att[d];
    for (int k = 0; k < Dn; ++k)
        acc = fmaf(v_s[k], W_att[d * Dn + k], acc);
    vlin0[b * Dn + d] = acc;
}

// ---------------------------------------------------------------------------
// a_tj[b][t] = sigmoid( vlin0[b,:] · values[b,t,:] )
// ---------------------------------------------------------------------------
__global__ void k_atj(const float* __restrict__ values, const float* __restrict__ vlin0,
                      float* __restrict__ a_tj) {
    int wid = threadIdx.x >> 6, lane = threadIdx.x & 63;
    int idx = blockIdx.x * 4 + wid;            // b*T + t
    int b = idx >> 9;
    const float4* vp = (const float4*)(values + (size_t)idx * Dn);
    const float4* qp = (const float4*)(vlin0 + b * Dn);
    float4 v = vp[lane], q = qp[lane];
    float s = v.x * q.x + v.y * q.y + v.z * q.z + v.w * q.w;
    #pragma unroll
    for (int off = 32; off; off >>= 1) s += __shfl_xor(s, off);
    if (lane == 0) a_tj[idx] = 1.0f / (1.0f + expf(-s));
}

// ---------------------------------------------------------------------------
// xW = values(bf16-converted in-kernel) @ W_cb^T + bias_c
// M=32768, N=1024, K=256. 128x128 tile, BK=32, 4 waves, mfma_f32_16x16x32_bf16.
// LDS chunk swizzle: slot(r,c) holds data chunk c at index c ^ ((r>>1)&3).
// ---------------------------------------------------------------------------
__global__ __launch_bounds__(256) void k_gemm(const float* __restrict__ A,
                                              const unsigned short* __restrict__ Bw,
                                              const float* __restrict__ bias,
                                              float* __restrict__ C) {
    __shared__ __align__(16) unsigned short As[128 * 32];
    __shared__ __align__(16) unsigned short Bs[128 * 32];
    const int tid = threadIdx.x;
    const int lane = tid & 63, wv = tid >> 6;
    const int wm = wv & 1, wn = wv >> 1;
    const int mBase = blockIdx.y * 128, nBase = blockIdx.x * 128;

    f32x4 acc[4][4];
    #pragma unroll
    for (int i = 0; i < 4; ++i)
        #pragma unroll
        for (int jj = 0; jj < 4; ++jj)
            acc[i][jj] = (f32x4){0.f, 0.f, 0.f, 0.f};

    for (int kb = 0; kb < 256; kb += 32) {
        // stage A (fp32 -> bf16), 2 passes of 8 floats per thread
        #pragma unroll
        for (int p = 0; p < 2; ++p) {
            int idx = p * 256 + tid;
            int r = idx >> 2, c = idx & 3;
            const float* src = A + (size_t)(mBase + r) * 256 + kb + c * 8;
            float4 f0 = *(const float4*)src;
            float4 f1 = *(const float4*)(src + 4);
            bf16x8 v;
            v[0] = (short)f2bf(f0.x); v[1] = (short)f2bf(f0.y);
            v[2] = (short)f2bf(f0.z); v[3] = (short)f2bf(f0.w);
            v[4] = (short)f2bf(f1.x); v[5] = (short)f2bf(f1.y);
            v[6] = (short)f2bf(f1.z); v[7] = (short)f2bf(f1.w);
            int cs = c ^ ((r >> 1) & 3);
            *(bf16x8*)&As[r * 32 + cs * 8] = v;
        }
        // stage B (already bf16)
        #pragma unroll
        for (int p = 0; p < 2; ++p) {
            int idx = p * 256 + tid;
            int r = idx >> 2, c = idx & 3;
            bf16x8 v = *(const bf16x8*)(Bw + (size_t)(nBase + r) * 256 + kb + c * 8);
            int cs = c ^ ((r >> 1) & 3);
            *(bf16x8*)&Bs[r * 32 + cs * 8] = v;
        }
        __syncthreads();

        bf16x8 af[4], bfr[4];
        #pragma unroll
        for (int f = 0; f < 4; ++f) {
            int ra = wm * 64 + f * 16 + (lane & 15);
            int ca = (lane >> 4) ^ ((ra >> 1) & 3);
            af[f] = *(const bf16x8*)&As[ra * 32 + ca * 8];
            int rb = wn * 64 + f * 16 + (lane & 15);
            int cb = (lane >> 4) ^ ((rb >> 1) & 3);
            bfr[f] = *(const bf16x8*)&Bs[rb * 32 + cb * 8];
        }
        #pragma unroll
        for (int fm = 0; fm < 4; ++fm)
            #pragma unroll
            for (int fn = 0; fn < 4; ++fn)
                acc[fm][fn] = __builtin_amdgcn_mfma_f32_16x16x32_bf16(af[fm], bfr[fn], acc[fm][fn], 0, 0, 0);
        __syncthreads();
    }
    // epilogue: C/D layout col=lane&15, row=(lane>>4)*4+reg
    #pragma unroll
    for (int fm = 0; fm < 4; ++fm) {
        #pragma unroll
        for (int fn = 0; fn < 4; ++fn) {
            #pragma unroll
            for (int r = 0; r < 4; ++r) {
                int row = mBase + wm * 64 + fm * 16 + (lane >> 4) * 4 + r;
                int col = nBase + wn * 64 + fn * 16 + (lane & 15);
                C[(size_t)row * Gn + col] = acc[fm][fn][r] + bias[col];
            }
        }
    }
}

// ---------------------------------------------------------------------------
// Recurrence: 1 WG (256 threads, 4 waves) per batch, 1 wave/SIMD (VGPR cap 512).
// Thread j owns unit j's 4 gate rows {j, j+256, j+512, j+768}.
// W_hh f16: k<192 in VGPRs (4 x 96 f16x2 = 384 regs), k in [192,256) in 128KB
// swizzled LDS. h exchanged via 8-deep f16 ring (1 barrier/step); out stores
// flushed from the ring every 8 steps to amortize the barrier's vmcnt drain.
// ---------------------------------------------------------------------------
__global__ __attribute__((amdgpu_flat_work_group_size(256, 256), amdgpu_waves_per_eu(1, 1)))
void k_rec(const float* __restrict__ xW,      // [B,T,1024] (all biases folded)
           const float* __restrict__ W_hh,    // [1024,256]
           const float* __restrict__ Deltas,  // [B,T,256]
           const float* __restrict__ a_tj,    // [B,T]
           float* __restrict__ out) {         // [B,T,256]
    extern __shared__ __align__(16) char smem[];
    unsigned int* Wl = (unsigned int*)smem;              // 1024*32*4 = 131072 B
    _Float16* hring = (_Float16*)(smem + 131072);        // 8*256*2   = 4096 B

    const int j = threadIdx.x;
    const int b = blockIdx.x;

    // ---- register weights: rows j+256*i, k in [0,192) ----
    f16x2 w[4][96];
    #pragma unroll
    for (int i = 0; i < 4; ++i) {
        const float4* p = (const float4*)(W_hh + (size_t)(j + 256 * i) * 256);
        #pragma unroll
        for (int q = 0; q < 48; ++q) {
            float4 v = p[q];
            w[i][2 * q + 0] = (f16x2){(_Float16)v.x, (_Float16)v.y};
            w[i][2 * q + 1] = (f16x2){(_Float16)v.z, (_Float16)v.w};
        }
    }
    // ---- LDS weights: k in [192,256), 32 f16-pairs/row, uint4-chunk swizzle ----
    for (int idx = j; idx < 1024 * 32; idx += 256) {
        int r = idx >> 5, p = idx & 31;
        int c = p >> 2, wi = p & 3;
        float2 wv = *(const float2*)(W_hh + (size_t)r * 256 + 192 + p * 2);
        Wl[r * 32 + (((c ^ (r & 7)) << 2) | wi)] = packh2(wv.x, wv.y);
    }

    float cst = 0.0f, c0, dcrun;
    const int s = j & 7;  // weight-LDS swizzle key (same for all 4 rows: 256%8==0)

    // ---- t = 0: h from x only; carry c stays 0 (faithful quirk), c_0 kept ----
    {
        size_t base = (size_t)b * Tn * Gn;
        float gi = xW[base + j];
        float gg = xW[base + 512 + j];
        float go = xW[base + 768 + j];
        dcrun = Deltas[(size_t)b * Tn * Dn + j];
        c0 = sigm(gi) * tanhf(gg);
        float h = sigm(go) * tanhf(c0);
        hring[0 * 256 + j] = (_Float16)h;
    }
    __syncthreads();

    // ---- main loop t = 1..511 ----
    for (int t = 1; t < Tn; ++t) {
        size_t xbase = ((size_t)b * Tn + t) * Gn;
        float xw0 = xW[xbase + j];
        float xw1 = xW[xbase + 256 + j];
        float xw2 = xW[xbase + 512 + j];
        float xw3 = xW[xbase + 768 + j];
        float del = Deltas[((size_t)b * Tn + t) * Dn + j];
        float at  = a_tj[b * Tn + t];

        const uint4* hb = (const uint4*)(hring + ((t - 1) & 7) * 256);
        float a0 = 0.f, a1 = 0.f, a2 = 0.f, a3 = 0.f;
        float b0 = 0.f, b1 = 0.f, b2 = 0.f, b3 = 0.f;

        // VGPR-resident K range [0,192)
        #pragma unroll
        for (int p4 = 0; p4 < 24; ++p4) {
            uint4 hv = hb[p4];
            f16x2 h0 = u2h(hv.x), h1 = u2h(hv.y), h2 = u2h(hv.z), h3 = u2h(hv.w);
            a0 = fdot2f(w[0][4 * p4 + 0], h0, a0); b0 = fdot2f(w[0][4 * p4 + 1], h1, b0);
            a0 = fdot2f(w[0][4 * p4 + 2], h2, a0); b0 = fdot2f(w[0][4 * p4 + 3], h3, b0);
            a1 = fdot2f(w[1][4 * p4 + 0], h0, a1); b1 = fdot2f(w[1][4 * p4 + 1], h1, b1);
            a1 = fdot2f(w[1][4 * p4 + 2], h2, a1); b1 = fdot2f(w[1][4 * p4 + 3], h3, b1);
            a2 = fdot2f(w[2][4 * p4 + 0], h0, a2); b2 = fdot2f(w[2][4 * p4 + 1], h1, b2);
            a2 = fdot2f(w[2][4 * p4 + 2], h2, a2); b2 = fdot2f(w[2][4 * p4 + 3], h3, b2);
            a3 = fdot2f(w[3][4 * p4 + 0], h0, a3); b3 = fdot2f(w[3][4 * p4 + 1], h1, b3);
            a3 = fdot2f(w[3][4 * p4 + 2], h2, a3); b3 = fdot2f(w[3][4 * p4 + 3], h3, b3);
        }
        // LDS-resident K range [192,256)
        {
            const uint4* wr0 = (const uint4*)&Wl[(size_t)(j)*32];
            const uint4* wr1 = (const uint4*)&Wl[(size_t)(j + 256) * 32];
            const uint4* wr2 = (const uint4*)&Wl[(size_t)(j + 512) * 32];
            const uint4* wr3 = (const uint4*)&Wl[(size_t)(j + 768) * 32];
            #pragma unroll
            for (int c = 0; c < 8; ++c) {
                uint4 hv = hb[24 + c];
                f16x2 h0 = u2h(hv.x), h1 = u2h(hv.y), h2 = u2h(hv.z), h3 = u2h(hv.w);
                uint4 w0 = wr0[c ^ s];
                a0 = fdot2f(u2h(w0.x), h0, a0); b0 = fdot2f(u2h(w0.y), h1, b0);
                a0 = fdot2f(u2h(w0.z), h2, a0); b0 = fdot2f(u2h(w0.w), h3, b0);
                uint4 w1 = wr1[c ^ s];
                a1 = fdot2f(u2h(w1.x), h0, a1); b1 = fdot2f(u2h(w1.y), h1, b1);
                a1 = fdot2f(u2h(w1.z), h2, a1); b1 = fdot2f(u2h(w1.w), h3, b1);
                uint4 w2 = wr2[c ^ s];
                a2 = fdot2f(u2h(w2.x), h0, a2); b2 = fdot2f(u2h(w2.y), h1, b2);
                a2 = fdot2f(u2h(w2.z), h2, a2); b2 = fdot2f(u2h(w2.w), h3, b2);
                uint4 w3 = wr3[c ^ s];
                a3 = fdot2f(u2h(w3.x), h0, a3); b3 = fdot2f(u2h(w3.y), h1, b3);
                a3 = fdot2f(u2h(w3.z), h2, a3); b3 = fdot2f(u2h(w3.w), h3, b3);
            }
        }
        float gi = xw0 + a0 + b0;
        float gf = xw1 + a1 + b1;
        float gg = xw2 + a2 + b2;
        float go = xw3 + a3 + b3;

        dcrun += del;
        float alpha = at / __logf(2.718281828459045f + dcrun);
        float cmix = alpha * c0 + (1.0f - alpha) * cst;
        cst = sigm(gf) * cmix + sigm(gi) * tanhf(gg);
        float h = sigm(go) * tanhf(cst);

        hring[(t & 7) * 256 + j] = (_Float16)h;
        if ((t & 7) == 7) {
            #pragma unroll
            for (int u = 0; u < 8; ++u) {
                int tt = t - 7 + u;
                out[((size_t)b * Tn + tt) * Hn + j] = (float)hring[u * 256 + j];
            }
        }
        __syncthreads();
    }
}

// ---------------------------------------------------------------------------
extern "C" void kernel_launch(void* const* d_in, const int* in_sizes, int n_in,
                              void* d_out, int out_size, void* d_ws, size_t ws_size,
                              hipStream_t stream) {
    const float* values = (const float*)d_in[0];
    const float* Deltas = (const float*)d_in[1];
    const float* W_att  = (const float*)d_in[2];
    const float* b_att  = (const float*)d_in[3];
    const float* W_ih   = (const float*)d_in[4];
    const float* W_hh   = (const float*)d_in[5];
    const float* b_ih   = (const float*)d_in[6];
    const float* b_hh   = (const float*)d_in[7];
    float* out = (float*)d_out;

    float* xW = (float*)d_ws;                                   // 33,554,432 f
    unsigned short* W_cb = (unsigned short*)(xW + (size_t)32768 * 1024); // 262,144 bf16
    float* bias_c = (float*)(W_cb + 1024 * 256);                // 1,024 f
    float* vlin0  = bias_c + 1024;                              // 16,384 f
    float* atj    = vlin0 + 64 * 256;                           // 32,768 f

    k_wc<<<1024, 256, 0, stream>>>(W_ih, W_att, b_att, b_ih, b_hh, W_cb, bias_c);
    k_vlin0<<<64, 256, 0, stream>>>(values, W_att, b_att, vlin0);
    k_atj<<<8192, 256, 0, stream>>>(values, vlin0, atj);
    k_gemm<<<dim3(8, 256), 256, 0, stream>>>(values, W_cb, bias_c, xW);
    k_rec<<<64, 256, 131072 + 4096, stream>>>(xW, W_hh, Deltas, atj, out);
}

// Round 3
// 1161.892 us; speedup vs baseline: 6.3711x; 6.3711x over previous
//
#include <hip/hip_runtime.h>
#include <math.h>

#define Bn 64
#define Tn 512
#define Dn 256
#define Hn 256
#define Gn 1024   // 4*H
#define KR 192    // h-dot K-range held in VGPRs
#define KL 64     // h-dot K-range held in LDS

typedef _Float16 f16x2 __attribute__((ext_vector_type(2)));
typedef short bf16x8 __attribute__((ext_vector_type(8)));
typedef float f32x4 __attribute__((ext_vector_type(4)));

union U32H2 { unsigned int u; f16x2 h; };

__device__ __forceinline__ f16x2 u2h(unsigned int u) { U32H2 v; v.u = u; return v.h; }
__device__ __forceinline__ unsigned int packh2(float x, float y) {
    U32H2 v; v.h = (f16x2){(_Float16)x, (_Float16)y}; return v.u;
}

// fp32 -> bf16 round-to-nearest-even
__device__ __forceinline__ unsigned short f2bf(float x) {
    unsigned int u = __float_as_uint(x);
    u = u + 0x7FFFu + ((u >> 16) & 1u);
    return (unsigned short)(u >> 16);
}

#if __has_builtin(__builtin_amdgcn_fdot2)
__device__ __forceinline__ float fdot2f(f16x2 a, f16x2 b, float c) {
    return __builtin_amdgcn_fdot2(a, b, c, false);
}
#else
__device__ __forceinline__ float fdot2f(f16x2 a, f16x2 b, float c) {
    return fmaf((float)a[1], (float)b[1], fmaf((float)a[0], (float)b[0], c));
}
#endif

__device__ __forceinline__ float sigm(float x) {
    return __fdividef(1.0f, 1.0f + __expf(-x));
}
__device__ __forceinline__ float tanh_fast(float x) {
    float xc = fminf(fmaxf(x, -15.0f), 15.0f);
    float e = __expf(2.0f * xc);
    return 1.0f - __fdividef(2.0f, e + 1.0f);
}

// ---------------------------------------------------------------------------
// W_c[g][k] (bf16) = sum_d W_ih[g][d]*W_att[d][k];  bias_c[g] = W_ih[g]·b_att + b_ih[g] + b_hh[g]
// ---------------------------------------------------------------------------
__global__ void k_wc(const float* __restrict__ W_ih, const float* __restrict__ W_att,
                     const float* __restrict__ b_att, const float* __restrict__ b_ih,
                     const float* __restrict__ b_hh,
                     unsigned short* __restrict__ W_cb, float* __restrict__ bias_c) {
    int g = blockIdx.x;
    int k = threadIdx.x;
    __shared__ float wih_s[Dn];
    __shared__ float red[256];
    wih_s[k] = W_ih[g * Dn + k];
    __syncthreads();
    float acc = 0.0f;
    for (int d = 0; d < Dn; ++d)
        acc = fmaf(wih_s[d], W_att[d * Dn + k], acc);
    W_cb[g * Dn + k] = f2bf(acc);
    red[k] = wih_s[k] * b_att[k];
    __syncthreads();
    for (int s = 128; s > 0; s >>= 1) {
        if (k < s) red[k] += red[k + s];
        __syncthreads();
    }
    if (k == 0) bias_c[g] = red[0] + b_ih[g] + b_hh[g];
}

// ---------------------------------------------------------------------------
// vlin0[b][d] = values[b,0,:]·W_att[d,:] + b_att[d]
// ---------------------------------------------------------------------------
__global__ void k_vlin0(const float* __restrict__ values, const float* __restrict__ W_att,
                        const float* __restrict__ b_att, float* __restrict__ vlin0) {
    int b = blockIdx.x, d = threadIdx.x;
    __shared__ float v_s[Dn];
    v_s[d] = values[(size_t)b * Tn * Dn + d];
    __syncthreads();
    float acc = b_att[d];
    for (int k = 0; k < Dn; ++k)
        acc = fmaf(v_s[k], W_att[d * Dn + k], acc);
    vlin0[b * Dn + d] = acc;
}

// ---------------------------------------------------------------------------
// a_tj[b][t] = sigmoid( vlin0[b,:] · values[b,t,:] )
// ---------------------------------------------------------------------------
__global__ void k_atj(const float* __restrict__ values, const float* __restrict__ vlin0,
                      float* __restrict__ a_tj) {
    int wid = threadIdx.x >> 6, lane = threadIdx.x & 63;
    int idx = blockIdx.x * 4 + wid;            // b*T + t
    int b = idx >> 9;
    const float4* vp = (const float4*)(values + (size_t)idx * Dn);
    const float4* qp = (const float4*)(vlin0 + b * Dn);
    float4 v = vp[lane], q = qp[lane];
    float s = v.x * q.x + v.y * q.y + v.z * q.z + v.w * q.w;
    #pragma unroll
    for (int off = 32; off; off >>= 1) s += __shfl_xor(s, off);
    if (lane == 0) a_tj[idx] = 1.0f / (1.0f + expf(-s));
}

// ---------------------------------------------------------------------------
// xW = values(bf16) @ W_cb^T + bias_c ; M=32768, N=1024, K=256
// 128x128 tile, BK=32, 4 waves, mfma_f32_16x16x32_bf16 (unchanged from r2)
// ---------------------------------------------------------------------------
__global__ __launch_bounds__(256) void k_gemm(const float* __restrict__ A,
                                              const unsigned short* __restrict__ Bw,
                                              const float* __restrict__ bias,
                                              float* __restrict__ C) {
    __shared__ __align__(16) unsigned short As[128 * 32];
    __shared__ __align__(16) unsigned short Bs[128 * 32];
    const int tid = threadIdx.x;
    const int lane = tid & 63, wv = tid >> 6;
    const int wm = wv & 1, wn = wv >> 1;
    const int mBase = blockIdx.y * 128, nBase = blockIdx.x * 128;

    f32x4 acc[4][4];
    #pragma unroll
    for (int i = 0; i < 4; ++i)
        #pragma unroll
        for (int jj = 0; jj < 4; ++jj)
            acc[i][jj] = (f32x4){0.f, 0.f, 0.f, 0.f};

    for (int kb = 0; kb < 256; kb += 32) {
        #pragma unroll
        for (int p = 0; p < 2; ++p) {
            int idx = p * 256 + tid;
            int r = idx >> 2, c = idx & 3;
            const float* src = A + (size_t)(mBase + r) * 256 + kb + c * 8;
            float4 f0 = *(const float4*)src;
            float4 f1 = *(const float4*)(src + 4);
            bf16x8 v;
            v[0] = (short)f2bf(f0.x); v[1] = (short)f2bf(f0.y);
            v[2] = (short)f2bf(f0.z); v[3] = (short)f2bf(f0.w);
            v[4] = (short)f2bf(f1.x); v[5] = (short)f2bf(f1.y);
            v[6] = (short)f2bf(f1.z); v[7] = (short)f2bf(f1.w);
            int cs = c ^ ((r >> 1) & 3);
            *(bf16x8*)&As[r * 32 + cs * 8] = v;
        }
        #pragma unroll
        for (int p = 0; p < 2; ++p) {
            int idx = p * 256 + tid;
            int r = idx >> 2, c = idx & 3;
            bf16x8 v = *(const bf16x8*)(Bw + (size_t)(nBase + r) * 256 + kb + c * 8);
            int cs = c ^ ((r >> 1) & 3);
            *(bf16x8*)&Bs[r * 32 + cs * 8] = v;
        }
        __syncthreads();

        bf16x8 af[4], bfr[4];
        #pragma unroll
        for (int f = 0; f < 4; ++f) {
            int ra = wm * 64 + f * 16 + (lane & 15);
            int ca = (lane >> 4) ^ ((ra >> 1) & 3);
            af[f] = *(const bf16x8*)&As[ra * 32 + ca * 8];
            int rb = wn * 64 + f * 16 + (lane & 15);
            int cb = (lane >> 4) ^ ((rb >> 1) & 3);
            bfr[f] = *(const bf16x8*)&Bs[rb * 32 + cb * 8];
        }
        #pragma unroll
        for (int fm = 0; fm < 4; ++fm)
            #pragma unroll
            for (int fn = 0; fn < 4; ++fn)
                acc[fm][fn] = __builtin_amdgcn_mfma_f32_16x16x32_bf16(af[fm], bfr[fn], acc[fm][fn], 0, 0, 0);
        __syncthreads();
    }
    #pragma unroll
    for (int fm = 0; fm < 4; ++fm) {
        #pragma unroll
        for (int fn = 0; fn < 4; ++fn) {
            #pragma unroll
            for (int r = 0; r < 4; ++r) {
                int row = mBase + wm * 64 + fm * 16 + (lane >> 4) * 4 + r;
                int col = nBase + wn * 64 + fn * 16 + (lane & 15);
                C[(size_t)row * Gn + col] = acc[fm][fn][r] + bias[col];
            }
        }
    }
}

// ---------------------------------------------------------------------------
// Recurrence v3: 1 WG (512 thr, 8 waves, 2/SIMD, 256-VGPR cap) per batch.
// Lane pair l / l^32 of each wave owns one unit's 4 gate rows:
//   e = (lane>>5); u = wave*32 + (lane&31); rows rA = e*512+u, rB = rA+256
//   (e=0 -> i,f rows; e=1 -> g,o rows). Gate exchange via 2 shfl_xor(.,32);
// nonlinearity computed redundantly by both lanes (same wave-inst = free).
// Weights f16: k<192 in VGPRs (2x96 regs), k in [192,256) in LDS chunk-major
// Wl4[chunk][row] (stride-1 b128 reads, conflict-free). h double-buffered f16,
// read as wave-uniform broadcast. One raw s_barrier + lgkmcnt(0) per step.
// ---------------------------------------------------------------------------
__global__ __attribute__((amdgpu_flat_work_group_size(512, 512), amdgpu_waves_per_eu(2, 2)))
void k_rec(const float* __restrict__ xW,      // [B,T,1024] (all biases folded)
           const float* __restrict__ W_hh,    // [1024,256]
           const float* __restrict__ Deltas,  // [B,T,256]
           const float* __restrict__ a_tj,    // [B,T]
           float* __restrict__ out) {         // [B,T,256]
    extern __shared__ __align__(16) char smem[];
    uint4*    Wl4  = (uint4*)smem;                    // [8][1024] = 131072 B
    _Float16* hbuf = (_Float16*)(smem + 131072);      // [2][256]  = 1024 B

    const int tid = threadIdx.x;
    const int b = blockIdx.x;
    const int l = tid & 63;
    const int e = l >> 5;                  // 0: i,f rows; 1: g,o rows
    const int u = (tid >> 6) * 32 + (l & 31);
    const int rA = e * 512 + u;
    const int rB = rA + 256;

    // ---- VGPR weights: rows rA,rB, k in [0,192) ----
    f16x2 wa[96], wb[96];
    {
        const float4* pA = (const float4*)(W_hh + (size_t)rA * 256);
        const float4* pB = (const float4*)(W_hh + (size_t)rB * 256);
        #pragma unroll
        for (int q = 0; q < 48; ++q) {
            float4 v = pA[q];
            wa[2 * q + 0] = (f16x2){(_Float16)v.x, (_Float16)v.y};
            wa[2 * q + 1] = (f16x2){(_Float16)v.z, (_Float16)v.w};
            float4 w = pB[q];
            wb[2 * q + 0] = (f16x2){(_Float16)w.x, (_Float16)w.y};
            wb[2 * q + 1] = (f16x2){(_Float16)w.z, (_Float16)w.w};
        }
    }
    // ---- LDS weights, chunk-major: Wl4[c][r] holds k = 192+8c .. 192+8c+7 of row r
    for (int idx = tid; idx < 8192; idx += 512) {
        int r = idx >> 3, c = idx & 7;
        const float* src = W_hh + (size_t)r * 256 + KR + c * 8;
        float4 f0 = *(const float4*)src;
        float4 f1 = *(const float4*)(src + 4);
        Wl4[c * 1024 + r] = (uint4){ packh2(f0.x, f0.y), packh2(f0.z, f0.w),
                                     packh2(f1.x, f1.y), packh2(f1.z, f1.w) };
    }

    float cst = 0.0f, c0, dcrun;

    // ---- t = 0: gates from xW only (h=0); carry c stays 0, c_0 kept ----
    {
        size_t xb = (size_t)b * Tn * Gn;
        float gA = xW[xb + rA];
        float gB = xW[xb + rB];
        float pA = __shfl_xor(gA, 32);
        float pB = __shfl_xor(gB, 32);
        float gi = e ? pA : gA;
        float gg = e ? gA : pA;
        float go = e ? gB : pB;
        dcrun = Deltas[(size_t)b * Tn * Dn + u];
        c0 = sigm(gi) * tanh_fast(gg);
        float h = sigm(go) * tanh_fast(c0);
        if (e == 0) {
            out[(size_t)b * Tn * Hn + u] = h;
            hbuf[u] = (_Float16)h;
        }
    }
    __syncthreads();

    // ---- main loop t = 1..511 ----
    #pragma unroll 1
    for (int t = 1; t < Tn; ++t) {
        size_t xb = ((size_t)b * Tn + t) * Gn;
        float xwA = xW[xb + rA];
        float xwB = xW[xb + rB];
        float del = Deltas[((size_t)b * Tn + t) * Dn + u];
        float at  = a_tj[b * Tn + t];

        const uint4* hp = (const uint4*)(hbuf + ((t + 1) & 1) * 256);
        float sA0 = 0.f, sA1 = 0.f, sB0 = 0.f, sB1 = 0.f;

        // LDS-resident K range [192,256): chunk-major, stride-1 across lanes
        {
            const uint4* WlA = Wl4 + rA;
            const uint4* WlB = Wl4 + rB;
            #pragma unroll
            for (int c = 0; c < 8; ++c) {
                uint4 hv = hp[24 + c];
                uint4 wva = WlA[c * 1024];
                uint4 wvb = WlB[c * 1024];
                sA0 = fdot2f(u2h(wva.x), u2h(hv.x), sA0);
                sA1 = fdot2f(u2h(wva.y), u2h(hv.y), sA1);
                sA0 = fdot2f(u2h(wva.z), u2h(hv.z), sA0);
                sA1 = fdot2f(u2h(wva.w), u2h(hv.w), sA1);
                sB0 = fdot2f(u2h(wvb.x), u2h(hv.x), sB0);
                sB1 = fdot2f(u2h(wvb.y), u2h(hv.y), sB1);
                sB0 = fdot2f(u2h(wvb.z), u2h(hv.z), sB0);
                sB1 = fdot2f(u2h(wvb.w), u2h(hv.w), sB1);
            }
        }
        // VGPR-resident K range [0,192)
        #pragma unroll
        for (int p = 0; p < 24; ++p) {
            uint4 hv = hp[p];
            f16x2 h0 = u2h(hv.x), h1 = u2h(hv.y), h2 = u2h(hv.z), h3 = u2h(hv.w);
            sA0 = fdot2f(wa[4 * p + 0], h0, sA0);
            sA1 = fdot2f(wa[4 * p + 1], h1, sA1);
            sA0 = fdot2f(wa[4 * p + 2], h2, sA0);
            sA1 = fdot2f(wa[4 * p + 3], h3, sA1);
            sB0 = fdot2f(wb[4 * p + 0], h0, sB0);
            sB1 = fdot2f(wb[4 * p + 1], h1, sB1);
            sB0 = fdot2f(wb[4 * p + 2], h2, sB0);
            sB1 = fdot2f(wb[4 * p + 3], h3, sB1);
        }

        float gA = xwA + sA0 + sA1;
        float gB = xwB + sB0 + sB1;
        float pA = __shfl_xor(gA, 32);
        float pB = __shfl_xor(gB, 32);
        float gi = e ? pA : gA;
        float gf = e ? pB : gB;
        float gg = e ? gA : pA;
        float go = e ? gB : pB;

        dcrun += del;
        float alpha = __fdividef(at, __logf(2.718281828459045f + dcrun));
        float cmix = alpha * c0 + (1.0f - alpha) * cst;
        cst = sigm(gf) * cmix + sigm(gi) * tanh_fast(gg);
        float h = sigm(go) * tanh_fast(cst);

        if (e == 0) {
            out[((size_t)b * Tn + t) * Hn + u] = h;
            hbuf[(t & 1) * 256 + u] = (_Float16)h;
        }
        // raw barrier: drain LDS writes only (no vmcnt drain of the out-store)
        asm volatile("s_waitcnt lgkmcnt(0)" ::: "memory");
        __builtin_amdgcn_s_barrier();
        __builtin_amdgcn_sched_barrier(0);
    }
}

// ---------------------------------------------------------------------------
extern "C" void kernel_launch(void* const* d_in, const int* in_sizes, int n_in,
                              void* d_out, int out_size, void* d_ws, size_t ws_size,
                              hipStream_t stream) {
    const float* values = (const float*)d_in[0];
    const float* Deltas = (const float*)d_in[1];
    const float* W_att  = (const float*)d_in[2];
    const float* b_att  = (const float*)d_in[3];
    const float* W_ih   = (const float*)d_in[4];
    const float* W_hh   = (const float*)d_in[5];
    const float* b_ih   = (const float*)d_in[6];
    const float* b_hh   = (const float*)d_in[7];
    float* out = (float*)d_out;

    float* xW = (float*)d_ws;                                   // 33,554,432 f
    unsigned short* W_cb = (unsigned short*)(xW + (size_t)32768 * 1024);
    float* bias_c = (float*)(W_cb + 1024 * 256);
    float* vlin0  = bias_c + 1024;
    float* atj    = vlin0 + 64 * 256;

    k_wc<<<1024, 256, 0, stream>>>(W_ih, W_att, b_att, b_ih, b_hh, W_cb, bias_c);
    k_vlin0<<<64, 256, 0, stream>>>(values, W_att, b_att, vlin0);
    k_atj<<<8192, 256, 0, stream>>>(values, vlin0, atj);
    k_gemm<<<dim3(8, 256), 256, 0, stream>>>(values, W_cb, bias_c, xW);
    k_rec<<<64, 512, 131072 + 1024, stream>>>(xW, W_hh, Deltas, atj, out);
}

// Round 4
// 1150.344 us; speedup vs baseline: 6.4350x; 1.0100x over previous
//
#include <hip/hip_runtime.h>
#include <math.h>

#define Bn 64
#define Tn 512
#define Dn 256
#define Hn 256
#define Gn 1024   // 4*H
#define KR 192    // h-dot K-range held in VGPRs
#define KL 64     // h-dot K-range held in LDS

typedef _Float16 f16x2 __attribute__((ext_vector_type(2)));
typedef short bf16x8 __attribute__((ext_vector_type(8)));
typedef float f32x4 __attribute__((ext_vector_type(4)));

union U32H2 { unsigned int u; f16x2 h; };

__device__ __forceinline__ f16x2 u2h(unsigned int u) { U32H2 v; v.u = u; return v.h; }
__device__ __forceinline__ unsigned int packh2(float x, float y) {
    U32H2 v; v.h = (f16x2){(_Float16)x, (_Float16)y}; return v.u;
}

// fp32 -> bf16 round-to-nearest-even
__device__ __forceinline__ unsigned short f2bf(float x) {
    unsigned int u = __float_as_uint(x);
    u = u + 0x7FFFu + ((u >> 16) & 1u);
    return (unsigned short)(u >> 16);
}

#if __has_builtin(__builtin_amdgcn_fdot2)
__device__ __forceinline__ float fdot2f(f16x2 a, f16x2 b, float c) {
    return __builtin_amdgcn_fdot2(a, b, c, false);
}
#else
__device__ __forceinline__ float fdot2f(f16x2 a, f16x2 b, float c) {
    return fmaf((float)a[1], (float)b[1], fmaf((float)a[0], (float)b[0], c));
}
#endif

__device__ __forceinline__ float sigm(float x) {
    return __fdividef(1.0f, 1.0f + __expf(-x));
}
__device__ __forceinline__ float tanh_fast(float x) {
    float xc = fminf(fmaxf(x, -15.0f), 15.0f);
    float e = __expf(2.0f * xc);
    return 1.0f - __fdividef(2.0f, e + 1.0f);
}

// ---------------------------------------------------------------------------
// W_c[g][k] (bf16) = sum_d W_ih[g][d]*W_att[d][k];  bias_c[g] = W_ih[g]·b_att + b_ih[g] + b_hh[g]
// ---------------------------------------------------------------------------
__global__ void k_wc(const float* __restrict__ W_ih, const float* __restrict__ W_att,
                     const float* __restrict__ b_att, const float* __restrict__ b_ih,
                     const float* __restrict__ b_hh,
                     unsigned short* __restrict__ W_cb, float* __restrict__ bias_c) {
    int g = blockIdx.x;
    int k = threadIdx.x;
    __shared__ float wih_s[Dn];
    __shared__ float red[256];
    wih_s[k] = W_ih[g * Dn + k];
    __syncthreads();
    float acc = 0.0f;
    for (int d = 0; d < Dn; ++d)
        acc = fmaf(wih_s[d], W_att[d * Dn + k], acc);
    W_cb[g * Dn + k] = f2bf(acc);
    red[k] = wih_s[k] * b_att[k];
    __syncthreads();
    for (int s = 128; s > 0; s >>= 1) {
        if (k < s) red[k] += red[k + s];
        __syncthreads();
    }
    if (k == 0) bias_c[g] = red[0] + b_ih[g] + b_hh[g];
}

// ---------------------------------------------------------------------------
// vlin0[b][d] = values[b,0,:]·W_att[d,:] + b_att[d]
// ---------------------------------------------------------------------------
__global__ void k_vlin0(const float* __restrict__ values, const float* __restrict__ W_att,
                        const float* __restrict__ b_att, float* __restrict__ vlin0) {
    int b = blockIdx.x, d = threadIdx.x;
    __shared__ float v_s[Dn];
    v_s[d] = values[(size_t)b * Tn * Dn + d];
    __syncthreads();
    float acc = b_att[d];
    for (int k = 0; k < Dn; ++k)
        acc = fmaf(v_s[k], W_att[d * Dn + k], acc);
    vlin0[b * Dn + d] = acc;
}

// ---------------------------------------------------------------------------
// a_tj[b][t] = sigmoid( vlin0[b,:] · values[b,t,:] )
// ---------------------------------------------------------------------------
__global__ void k_atj(const float* __restrict__ values, const float* __restrict__ vlin0,
                      float* __restrict__ a_tj) {
    int wid = threadIdx.x >> 6, lane = threadIdx.x & 63;
    int idx = blockIdx.x * 4 + wid;            // b*T + t
    int b = idx >> 9;
    const float4* vp = (const float4*)(values + (size_t)idx * Dn);
    const float4* qp = (const float4*)(vlin0 + b * Dn);
    float4 v = vp[lane], q = qp[lane];
    float s = v.x * q.x + v.y * q.y + v.z * q.z + v.w * q.w;
    #pragma unroll
    for (int off = 32; off; off >>= 1) s += __shfl_xor(s, off);
    if (lane == 0) a_tj[idx] = 1.0f / (1.0f + expf(-s));
}

// ---------------------------------------------------------------------------
// xW = values(bf16) @ W_cb^T + bias_c ; M=32768, N=1024, K=256
// 128x128 tile, BK=32, 4 waves, mfma_f32_16x16x32_bf16
// ---------------------------------------------------------------------------
__global__ __launch_bounds__(256) void k_gemm(const float* __restrict__ A,
                                              const unsigned short* __restrict__ Bw,
                                              const float* __restrict__ bias,
                                              float* __restrict__ C) {
    __shared__ __align__(16) unsigned short As[128 * 32];
    __shared__ __align__(16) unsigned short Bs[128 * 32];
    const int tid = threadIdx.x;
    const int lane = tid & 63, wv = tid >> 6;
    const int wm = wv & 1, wn = wv >> 1;
    const int mBase = blockIdx.y * 128, nBase = blockIdx.x * 128;

    f32x4 acc[4][4];
    #pragma unroll
    for (int i = 0; i < 4; ++i)
        #pragma unroll
        for (int jj = 0; jj < 4; ++jj)
            acc[i][jj] = (f32x4){0.f, 0.f, 0.f, 0.f};

    for (int kb = 0; kb < 256; kb += 32) {
        #pragma unroll
        for (int p = 0; p < 2; ++p) {
            int idx = p * 256 + tid;
            int r = idx >> 2, c = idx & 3;
            const float* src = A + (size_t)(mBase + r) * 256 + kb + c * 8;
            float4 f0 = *(const float4*)src;
            float4 f1 = *(const float4*)(src + 4);
            bf16x8 v;
            v[0] = (short)f2bf(f0.x); v[1] = (short)f2bf(f0.y);
            v[2] = (short)f2bf(f0.z); v[3] = (short)f2bf(f0.w);
            v[4] = (short)f2bf(f1.x); v[5] = (short)f2bf(f1.y);
            v[6] = (short)f2bf(f1.z); v[7] = (short)f2bf(f1.w);
            int cs = c ^ ((r >> 1) & 3);
            *(bf16x8*)&As[r * 32 + cs * 8] = v;
        }
        #pragma unroll
        for (int p = 0; p < 2; ++p) {
            int idx = p * 256 + tid;
            int r = idx >> 2, c = idx & 3;
            bf16x8 v = *(const bf16x8*)(Bw + (size_t)(nBase + r) * 256 + kb + c * 8);
            int cs = c ^ ((r >> 1) & 3);
            *(bf16x8*)&Bs[r * 32 + cs * 8] = v;
        }
        __syncthreads();

        bf16x8 af[4], bfr[4];
        #pragma unroll
        for (int f = 0; f < 4; ++f) {
            int ra = wm * 64 + f * 16 + (lane & 15);
            int ca = (lane >> 4) ^ ((ra >> 1) & 3);
            af[f] = *(const bf16x8*)&As[ra * 32 + ca * 8];
            int rb = wn * 64 + f * 16 + (lane & 15);
            int cb = (lane >> 4) ^ ((rb >> 1) & 3);
            bfr[f] = *(const bf16x8*)&Bs[rb * 32 + cb * 8];
        }
        #pragma unroll
        for (int fm = 0; fm < 4; ++fm)
            #pragma unroll
            for (int fn = 0; fn < 4; ++fn)
                acc[fm][fn] = __builtin_amdgcn_mfma_f32_16x16x32_bf16(af[fm], bfr[fn], acc[fm][fn], 0, 0, 0);
        __syncthreads();
    }
    #pragma unroll
    for (int fm = 0; fm < 4; ++fm) {
        #pragma unroll
        for (int fn = 0; fn < 4; ++fn) {
            #pragma unroll
            for (int r = 0; r < 4; ++r) {
                int row = mBase + wm * 64 + fm * 16 + (lane >> 4) * 4 + r;
                int col = nBase + wn * 64 + fn * 16 + (lane & 15);
                C[(size_t)row * Gn + col] = acc[fm][fn][r] + bias[col];
            }
        }
    }
}

// ---------------------------------------------------------------------------
// Recurrence v4: identical structure to v3, but waves_per_eu(1,1) so the
// backend budgets 256 ArchVGPRs/thread (empirical law: budget = 256/min_waves).
// 8 waves x <=256 VGPR = full 512-reg/SIMD pool -> still 2 waves/SIMD resident.
// Live set ~230 regs -> no spill.
// ---------------------------------------------------------------------------
__global__ __attribute__((amdgpu_flat_work_group_size(512, 512), amdgpu_waves_per_eu(1, 1)))
void k_rec(const float* __restrict__ xW,      // [B,T,1024] (all biases folded)
           const float* __restrict__ W_hh,    // [1024,256]
           const float* __restrict__ Deltas,  // [B,T,256]
           const float* __restrict__ a_tj,    // [B,T]
           float* __restrict__ out) {         // [B,T,256]
    extern __shared__ __align__(16) char smem[];
    uint4*    Wl4  = (uint4*)smem;                    // [8][1024] = 131072 B
    _Float16* hbuf = (_Float16*)(smem + 131072);      // [2][256]  = 1024 B

    const int tid = threadIdx.x;
    const int b = blockIdx.x;
    const int l = tid & 63;
    const int e = l >> 5;                  // 0: i,f rows; 1: g,o rows
    const int u = (tid >> 6) * 32 + (l & 31);
    const int rA = e * 512 + u;
    const int rB = rA + 256;

    // ---- VGPR weights: rows rA,rB, k in [0,192) ----
    f16x2 wa[96], wb[96];
    {
        const float4* pA = (const float4*)(W_hh + (size_t)rA * 256);
        const float4* pB = (const float4*)(W_hh + (size_t)rB * 256);
        #pragma unroll
        for (int q = 0; q < 48; ++q) {
            float4 v = pA[q];
            wa[2 * q + 0] = (f16x2){(_Float16)v.x, (_Float16)v.y};
            wa[2 * q + 1] = (f16x2){(_Float16)v.z, (_Float16)v.w};
            float4 w = pB[q];
            wb[2 * q + 0] = (f16x2){(_Float16)w.x, (_Float16)w.y};
            wb[2 * q + 1] = (f16x2){(_Float16)w.z, (_Float16)w.w};
        }
    }
    // ---- LDS weights, chunk-major: Wl4[c][r] holds k = 192+8c .. 192+8c+7 of row r
    for (int idx = tid; idx < 8192; idx += 512) {
        int r = idx >> 3, c = idx & 7;
        const float* src = W_hh + (size_t)r * 256 + KR + c * 8;
        float4 f0 = *(const float4*)src;
        float4 f1 = *(const float4*)(src + 4);
        Wl4[c * 1024 + r] = (uint4){ packh2(f0.x, f0.y), packh2(f0.z, f0.w),
                                     packh2(f1.x, f1.y), packh2(f1.z, f1.w) };
    }

    float cst = 0.0f, c0, dcrun;

    // ---- t = 0: gates from xW only (h=0); carry c stays 0, c_0 kept ----
    {
        size_t xb = (size_t)b * Tn * Gn;
        float gA = xW[xb + rA];
        float gB = xW[xb + rB];
        float pA = __shfl_xor(gA, 32);
        float pB = __shfl_xor(gB, 32);
        float gi = e ? pA : gA;
        float gg = e ? gA : pA;
        float go = e ? gB : pB;
        dcrun = Deltas[(size_t)b * Tn * Dn + u];
        c0 = sigm(gi) * tanh_fast(gg);
        float h = sigm(go) * tanh_fast(c0);
        if (e == 0) {
            out[(size_t)b * Tn * Hn + u] = h;
            hbuf[u] = (_Float16)h;
        }
    }
    __syncthreads();

    // ---- main loop t = 1..511 ----
    #pragma unroll 1
    for (int t = 1; t < Tn; ++t) {
        size_t xb = ((size_t)b * Tn + t) * Gn;
        float xwA = xW[xb + rA];
        float xwB = xW[xb + rB];
        float del = Deltas[((size_t)b * Tn + t) * Dn + u];
        float at  = a_tj[b * Tn + t];

        const uint4* hp = (const uint4*)(hbuf + ((t + 1) & 1) * 256);
        float sA0 = 0.f, sA1 = 0.f, sB0 = 0.f, sB1 = 0.f;

        // LDS-resident K range [192,256): chunk-major, stride-1 across lanes
        {
            const uint4* WlA = Wl4 + rA;
            const uint4* WlB = Wl4 + rB;
            #pragma unroll
            for (int c = 0; c < 8; ++c) {
                uint4 hv = hp[24 + c];
                uint4 wva = WlA[c * 1024];
                uint4 wvb = WlB[c * 1024];
                sA0 = fdot2f(u2h(wva.x), u2h(hv.x), sA0);
                sA1 = fdot2f(u2h(wva.y), u2h(hv.y), sA1);
                sA0 = fdot2f(u2h(wva.z), u2h(hv.z), sA0);
                sA1 = fdot2f(u2h(wva.w), u2h(hv.w), sA1);
                sB0 = fdot2f(u2h(wvb.x), u2h(hv.x), sB0);
                sB1 = fdot2f(u2h(wvb.y), u2h(hv.y), sB1);
                sB0 = fdot2f(u2h(wvb.z), u2h(hv.z), sB0);
                sB1 = fdot2f(u2h(wvb.w), u2h(hv.w), sB1);
            }
        }
        // VGPR-resident K range [0,192)
        #pragma unroll
        for (int p = 0; p < 24; ++p) {
            uint4 hv = hp[p];
            f16x2 h0 = u2h(hv.x), h1 = u2h(hv.y), h2 = u2h(hv.z), h3 = u2h(hv.w);
            sA0 = fdot2f(wa[4 * p + 0], h0, sA0);
            sA1 = fdot2f(wa[4 * p + 1], h1, sA1);
            sA0 = fdot2f(wa[4 * p + 2], h2, sA0);
            sA1 = fdot2f(wa[4 * p + 3], h3, sA1);
            sB0 = fdot2f(wb[4 * p + 0], h0, sB0);
            sB1 = fdot2f(wb[4 * p + 1], h1, sB1);
            sB0 = fdot2f(wb[4 * p + 2], h2, sB0);
            sB1 = fdot2f(wb[4 * p + 3], h3, sB1);
        }

        float gA = xwA + sA0 + sA1;
        float gB = xwB + sB0 + sB1;
        float pA = __shfl_xor(gA, 32);
        float pB = __shfl_xor(gB, 32);
        float gi = e ? pA : gA;
        float gf = e ? pB : gB;
        float gg = e ? gA : pA;
        float go = e ? gB : pB;

        dcrun += del;
        float alpha = __fdividef(at, __logf(2.718281828459045f + dcrun));
        float cmix = alpha * c0 + (1.0f - alpha) * cst;
        cst = sigm(gf) * cmix + sigm(gi) * tanh_fast(gg);
        float h = sigm(go) * tanh_fast(cst);

        if (e == 0) {
            out[((size_t)b * Tn + t) * Hn + u] = h;
            hbuf[(t & 1) * 256 + u] = (_Float16)h;
        }
        // raw barrier: drain LDS writes only (no vmcnt drain of the out-store)
        asm volatile("s_waitcnt lgkmcnt(0)" ::: "memory");
        __builtin_amdgcn_s_barrier();
        __builtin_amdgcn_sched_barrier(0);
    }
}

// ---------------------------------------------------------------------------
extern "C" void kernel_launch(void* const* d_in, const int* in_sizes, int n_in,
                              void* d_out, int out_size, void* d_ws, size_t ws_size,
                              hipStream_t stream) {
    const float* values = (const float*)d_in[0];
    const float* Deltas = (const float*)d_in[1];
    const float* W_att  = (const float*)d_in[2];
    const float* b_att  = (const float*)d_in[3];
    const float* W_ih   = (const float*)d_in[4];
    const float* W_hh   = (const float*)d_in[5];
    const float* b_ih   = (const float*)d_in[6];
    const float* b_hh   = (const float*)d_in[7];
    float* out = (float*)d_out;

    float* xW = (float*)d_ws;                                   // 33,554,432 f
    unsigned short* W_cb = (unsigned short*)(xW + (size_t)32768 * 1024);
    float* bias_c = (float*)(W_cb + 1024 * 256);
    float* vlin0  = bias_c + 1024;
    float* atj    = vlin0 + 64 * 256;

    k_wc<<<1024, 256, 0, stream>>>(W_ih, W_att, b_att, b_ih, b_hh, W_cb, bias_c);
    k_vlin0<<<64, 256, 0, stream>>>(values, W_att, b_att, vlin0);
    k_atj<<<8192, 256, 0, stream>>>(values, vlin0, atj);
    k_gemm<<<dim3(8, 256), 256, 0, stream>>>(values, W_cb, bias_c, xW);
    k_rec<<<64, 512, 131072 + 1024, stream>>>(xW, W_hh, Deltas, atj, out);
}